// Round 9
// baseline (336.052 us; speedup 1.0000x reference)
//
#include <hip/hip_runtime.h>

#define N_DRUG 572
#define DIM 512
#define MAXDEG 32
#define FSB 12                      // fs row stride in BYTES (2 cols + 1 pad)
#define ORIG_OFF (573 * FSB)        // orig[] base inside fsb (6876)
#define DUMMY_ORIG (ORIG_OFF + 572 * FSB)   // zeroed orig dummy row (13740)
#define SLOTS 588                   // 572 perm slots + 16 pad

// ---------------------------------------------------------------------------
// prep_kernel: one launch, three independent jobs split by block range.
//  blocks [0,512):   pack linW into K-major panels linP.
//  blocks [512,928): relaP[200][512] = relaW @ Wa^T.
//  block 928:        LEVEL-BASED scan schedule. orig/new split removes
//    anti-deps, so any topological order by dependency level is exact.
//    Emits: sched_g[0]=nrounds; [1..572]=perm (level-sorted node order);
//    [573..573+nrounds+1]=per-round counts (chunks of <=16 within a level).
// ---------------------------------------------------------------------------
__global__ __launch_bounds__(256) void prep_kernel(
    const float* __restrict__ Wa, const float* __restrict__ relaW,
    const float* __restrict__ linW, const int* __restrict__ nbr_idx,
    const int* __restrict__ nbr_deg, float* __restrict__ linP,
    float* __restrict__ relaP, int* __restrict__ sched_g)
{
    const int b = blockIdx.x;
    const int t = threadIdx.x;
    if (b < 512) {                          // ---- pack linW ----
        const int g = b * 256 + t;          // [0,131072)
        const int c = g & 511, k4 = g >> 9; // k4 in [0,256)
        const float4 v = make_float4(linW[(size_t)(k4 * 4 + 0) * 512 + c],
                                     linW[(size_t)(k4 * 4 + 1) * 512 + c],
                                     linW[(size_t)(k4 * 4 + 2) * 512 + c],
                                     linW[(size_t)(k4 * 4 + 3) * 512 + c]);
        *(float4*)&linP[((size_t)(c >> 6) * 256 + k4) * 256 + (c & 63) * 4] = v;
        return;
    }
    if (b == 928) {                         // ---- level schedule ----
        __shared__ unsigned short lowN[N_DRUG * MAXDEG];  // lower-nbr lists
        __shared__ unsigned char  lowC[N_DRUG];
        __shared__ short lvl[N_DRUG];
        __shared__ int hist[N_DRUG];
        __shared__ int off0[N_DRUG];
        __shared__ int cntL[N_DRUG];
        __shared__ int chg;

        for (int i = t; i < N_DRUG; i += 256) {
            const int d = nbr_deg[i];
            const int4* np = (const int4*)&nbr_idx[i * MAXDEG];
            int c = 0;
            unsigned short* lp = &lowN[i * MAXDEG];
            #pragma unroll
            for (int u = 0; u < 8; ++u) {
                const int4 qq = np[u];
                const int bb = u * 4;
                if (bb + 0 < d && qq.x < i) lp[c++] = (unsigned short)qq.x;
                if (bb + 1 < d && qq.y < i) lp[c++] = (unsigned short)qq.y;
                if (bb + 2 < d && qq.z < i) lp[c++] = (unsigned short)qq.z;
                if (bb + 3 < d && qq.w < i) lp[c++] = (unsigned short)qq.w;
            }
            lowC[i] = (unsigned char)c;
            lvl[i] = 0;
            hist[i] = 0; cntL[i] = 0;
        }
        __syncthreads();
        // chaotic Gauss-Seidel relaxation to longest-path levels (monotone)
        for (int it = 0; it < 600; ++it) {
            if (t == 0) chg = 0;
            __syncthreads();
            for (int i = t; i < N_DRUG; i += 256) {
                const int c = lowC[i];
                int m = -1;
                for (int u = 0; u < c; ++u) m = max(m, (int)lvl[lowN[i * MAXDEG + u]]);
                if (m + 1 > (int)lvl[i]) { lvl[i] = (short)(m + 1); chg = 1; }
            }
            __syncthreads();
            if (!chg) break;
        }
        for (int i = t; i < N_DRUG; i += 256) atomicAdd(&hist[lvl[i]], 1);
        __syncthreads();
        if (t == 0) {                        // prefix + round emission
            int acc = 0, nr = 0;
            for (int L = 0; L < N_DRUG; ++L) {
                off0[L] = acc;
                int w = hist[L];
                acc += w;
                while (w > 0) { const int c = min(w, 16); sched_g[573 + nr] = c; ++nr; w -= c; }
            }
            sched_g[0] = nr;
            sched_g[573 + nr] = 0;
            sched_g[573 + nr + 1] = 0;
        }
        __syncthreads();
        for (int i = t; i < N_DRUG; i += 256) {   // scatter perm (level-sorted)
            const int p = off0[lvl[i]] + atomicAdd(&cntL[lvl[i]], 1);
            sched_g[1 + p] = i;
        }
        return;
    }
    // ---- relaP = relaW @ Wa^T ----
    const int bb = b - 512;                 // [0,416): 13 r-groups x 32 k-panels
    const int rb = bb >> 5, kb = bb & 31;
    const int wv = t >> 6, l = t & 63;
    const int r0 = rb * 16 + wv * 4;        // 4 rows per wave
    const int k0 = kb * 16;                 // 16 output cols per wave

    float a[4][8];
    #pragma unroll
    for (int rr = 0; rr < 4; ++rr) {
        const float4* ap = (const float4*)(relaW + (size_t)min(r0 + rr, 199) * 512 + l * 8);
        const float4 x = ap[0], y = ap[1];
        a[rr][0] = x.x; a[rr][1] = x.y; a[rr][2] = x.z; a[rr][3] = x.w;
        a[rr][4] = y.x; a[rr][5] = y.y; a[rr][6] = y.z; a[rr][7] = y.w;
    }
    float acc[64];
    #pragma unroll
    for (int i = 0; i < 64; ++i) acc[i] = 0.f;
    #pragma unroll
    for (int kk = 0; kk < 16; ++kk) {
        const float4* bp = (const float4*)(Wa + (size_t)(k0 + kk) * 512 + l * 8);
        const float4 x = bp[0], y = bp[1];
        const float bv[8] = {x.x, x.y, x.z, x.w, y.x, y.y, y.z, y.w};
        #pragma unroll
        for (int rr = 0; rr < 4; ++rr) {
            float s = acc[rr * 16 + kk];
            #pragma unroll
            for (int j = 0; j < 8; ++j) s = fmaf(a[rr][j], bv[j], s);
            acc[rr * 16 + kk] = s;
        }
    }
    #pragma unroll
    for (int off = 1; off <= 32; off <<= 1) {
        #pragma unroll
        for (int i = 0; i < 64; ++i) acc[i] += __shfl_xor(acc[i], off, 64);
    }
    float outv = acc[0];
    #pragma unroll
    for (int i = 1; i < 64; ++i) outv = (l == i) ? acc[i] : outv;
    const int rr = l >> 4, kk = l & 15;
    if (r0 + rr < 200) relaP[(size_t)(r0 + rr) * 512 + k0 + kk] = outv;
}

// ---------------------------------------------------------------------------
// attn v2: one block per drug. scores -> softmax -> agg (split-K, float4
// gathers: 16B/lane coalescing sweet spot, half the vmem instructions of the
// float2 version on the HBM-bound phase).
// ---------------------------------------------------------------------------
__global__ __launch_bounds__(256) void attn_kernel(
    const float* __restrict__ drugW, const float* __restrict__ relaP,
    const float* __restrict__ entW, const int* __restrict__ dn,
    const int* __restrict__ adj_tail, const int* __restrict__ adj_rel,
    float* __restrict__ cat)
{
    __shared__ float at[64];
    __shared__ int tails[64];
    __shared__ int rels[64];
    __shared__ float part[512];
    const int d = blockIdx.x;
    const int t = threadIdx.x;
    const int w = t >> 6, lane = t & 63;

    if (t < 64) {
        tails[t] = adj_tail[d * 64 + t];
        rels[t]  = adj_rel[d * 64 + t];
    }
    const int rd = dn[d];
    float qv[8];
    {
        const float4* qp = (const float4*)(drugW + (size_t)rd * 512 + lane * 8);
        const float4 x = qp[0], y = qp[1];
        qv[0] = x.x; qv[1] = x.y; qv[2] = x.z; qv[3] = x.w;
        qv[4] = y.x; qv[5] = y.y; qv[6] = y.z; qv[7] = y.w;
    }
    __syncthreads();

    #pragma unroll 4
    for (int kk = 0; kk < 16; ++kk) {
        const int k = w * 16 + kk;
        const float4* p = (const float4*)(relaP + (size_t)rels[k] * 512 + lane * 8);
        const float4 x = p[0], y = p[1];
        float s = 0.f;
        s = fmaf(qv[0], x.x, s); s = fmaf(qv[1], x.y, s);
        s = fmaf(qv[2], x.z, s); s = fmaf(qv[3], x.w, s);
        s = fmaf(qv[4], y.x, s); s = fmaf(qv[5], y.y, s);
        s = fmaf(qv[6], y.z, s); s = fmaf(qv[7], y.w, s);
        #pragma unroll
        for (int off = 32; off >= 1; off >>= 1) s += __shfl_xor(s, off, 64);
        if (lane == 0) at[k] = s * 0.0441941738241592f;   // 1/sqrt(512)
    }
    __syncthreads();

    if (w == 0) {
        const float s = at[lane];
        float m = s;
        #pragma unroll
        for (int off = 32; off >= 1; off >>= 1) m = fmaxf(m, __shfl_xor(m, off, 64));
        const float e = __expf(s - m);
        float sum = e;
        #pragma unroll
        for (int off = 32; off >= 1; off >>= 1) sum += __shfl_xor(sum, off, 64);
        at[lane] = e / sum;
    }
    __syncthreads();

    // agg: 2-way K-split, thread owns 4 cols, float4 gathers
    {
        const int kh = t >> 7;            // k-half 0/1
        const int c4 = (t & 127) * 4;
        float a0 = 0.f, a1 = 0.f, a2 = 0.f, a3 = 0.f;
        #pragma unroll 8
        for (int kk = 0; kk < 32; ++kk) {
            const int k = kh * 32 + kk;
            const float ak = at[k];
            const float4 e = *(const float4*)(entW + (size_t)tails[k] * 512 + c4);
            a0 = fmaf(ak, e.x, a0); a1 = fmaf(ak, e.y, a1);
            a2 = fmaf(ak, e.z, a2); a3 = fmaf(ak, e.w, a3);
        }
        if (kh == 1) *(float4*)&part[c4] = make_float4(a0, a1, a2, a3);
        __syncthreads();
        if (kh == 0) {
            const float4 p = *(const float4*)&part[c4];
            float* o = cat + (size_t)d * 1024;
            *(float4*)&o[c4] = make_float4(a0 + p.x, a1 + p.y, a2 + p.z, a3 + p.w);
            const float4 de = *(const float4*)(drugW + (size_t)rd * 512 + c4);
            *(float4*)&o[512 + c4] = de;
        }
    }
}

// ---------------------------------------------------------------------------
// gemm_h v4: out[572][512] = ReLU(cat @ linW + b). (unchanged from round 8)
// ---------------------------------------------------------------------------
__global__ __launch_bounds__(512) void gemm_h(
    const float* __restrict__ A, const float* __restrict__ linP,
    const float* __restrict__ bias, float* __restrict__ out)
{
    __shared__ float red[8][8][128];      // 32 KB
    const int t = threadIdx.x;
    const int wv = t >> 6, lane = t & 63;
    const int r0 = blockIdx.x * 8;
    const int half = lane >> 5;
    const int cw = (lane * 2) & 63;

    const float* wp = linP + ((size_t)(blockIdx.y * 2 + half) * 256 + wv * 32) * 256
                    + cw * 4;
    const float* ap[8];
    #pragma unroll
    for (int r = 0; r < 8; ++r)
        ap[r] = A + (size_t)min(r0 + r, N_DRUG - 1) * 1024 + wv * 128;

    float acc0[8] = {0.f, 0.f, 0.f, 0.f, 0.f, 0.f, 0.f, 0.f};
    float acc1[8] = {0.f, 0.f, 0.f, 0.f, 0.f, 0.f, 0.f, 0.f};

    float4 wa = *(const float4*)(wp);
    float4 wb = *(const float4*)(wp + 4);
    float4 aa[8];
    #pragma unroll
    for (int r = 0; r < 8; ++r) aa[r] = *(const float4*)(ap[r]);

    for (int k4 = 0; k4 < 32; ++k4) {
        const int kn = (k4 + 1) & 31;
        const float4 wan = *(const float4*)(wp + (size_t)kn * 256);
        const float4 wbn = *(const float4*)(wp + (size_t)kn * 256 + 4);
        float4 an[8];
        #pragma unroll
        for (int r = 0; r < 8; ++r) an[r] = *(const float4*)(ap[r] + kn * 4);

        #pragma unroll
        for (int r = 0; r < 8; ++r) {
            const float4 a = aa[r];
            acc0[r] = fmaf(a.x, wa.x, acc0[r]);
            acc0[r] = fmaf(a.y, wa.y, acc0[r]);
            acc0[r] = fmaf(a.z, wa.z, acc0[r]);
            acc0[r] = fmaf(a.w, wa.w, acc0[r]);
            acc1[r] = fmaf(a.x, wb.x, acc1[r]);
            acc1[r] = fmaf(a.y, wb.y, acc1[r]);
            acc1[r] = fmaf(a.z, wb.z, acc1[r]);
            acc1[r] = fmaf(a.w, wb.w, acc1[r]);
        }
        wa = wan; wb = wbn;
        #pragma unroll
        for (int r = 0; r < 8; ++r) aa[r] = an[r];
    }

    #pragma unroll
    for (int r = 0; r < 8; ++r)
        *(float2*)&red[wv][r][lane * 2] = make_float2(acc0[r], acc1[r]);
    __syncthreads();

    #pragma unroll
    for (int u = 0; u < 2; ++u) {
        const int o = u * 512 + t;
        const int r = o >> 7, cc = o & 127;
        if (r0 + r < N_DRUG) {
            float v = red[0][r][cc];
            #pragma unroll
            for (int w = 1; w < 8; ++w) v += red[w][r][cc];
            v += bias[blockIdx.y * 128 + cc];
            out[(size_t)(r0 + r) * 512 + blockIdx.y * 128 + cc] = fmaxf(v, 0.f);
        }
    }
}

// ---------------------------------------------------------------------------
// scan v5: one wave per block, 2 cols, 256 blocks. Level-scheduled rounds
// over an orig/new split:
//   new[i] = F(new[nbr<i], orig[nbr>=i], orig[i])   (== sequential in-place)
// Tables are PRE-PERMUTED into processing order (perm from prep), offsets
// carry the orig/new base and column shift, so the round body is just:
// 16 gathers + next-slot prefetch + DPP combine + fmaf + write.
// ---------------------------------------------------------------------------
__global__ __launch_bounds__(64) void scan_kernel(
    float* hout, const float* __restrict__ gamma, const float* __restrict__ beta,
    const int* __restrict__ nbr_idx, const int* __restrict__ nbr_deg,
    const int* __restrict__ epoch, const int* __restrict__ sched_g)
{
    __shared__ alignas(16) unsigned char fsb[2 * ORIG_OFF + 16];      // new|orig
    __shared__ alignas(16) unsigned short offsPA[SLOTS * MAXDEG];     // 37.6 KB
    __shared__ alignas(16) unsigned short offsPB[SLOTS * MAXDEG];     // 37.6 KB
    __shared__ float2 ivwP[SLOTS];
    __shared__ unsigned short selfP[SLOTS];
    __shared__ int rcnt[576];

    const int lane = threadIdx.x;      // 0..63
    const int col  = lane & 1;
    const int rg   = lane >> 1;
    const int c0   = blockIdx.x * 2;
    const int cl4  = col * 4;

    const int nrounds = sched_g[0];
    for (int i = lane; i < 576; i += 64) rcnt[i] = (i < nrounds) ? sched_g[573 + i] : 0;

    // ---- permuted tables: slot s processes node perm[s] ----
    for (int s = lane; s < SLOTS; s += 64) {
        const int node = (s < N_DRUG) ? sched_g[1 + s] : N_DRUG;
        uint2* opA = (uint2*)&offsPA[s * MAXDEG];
        uint2* opB = (uint2*)&offsPB[s * MAXDEG];
        if (node < N_DRUG) {
            const int d = nbr_deg[node];
            ivwP[s] = (d > 0) ? make_float2(0.5f / (float)d, 0.5f)
                              : make_float2(0.f, 1.f);
            selfP[s] = (unsigned short)(node * FSB);
            const int4* np = (const int4*)&nbr_idx[node * MAXDEG];
            #pragma unroll
            for (int u = 0; u < 8; ++u) {
                const int4 qq = np[u];
                const int b = u * 4;
                unsigned o[4];
                const int nn[4] = {qq.x, qq.y, qq.z, qq.w};
                #pragma unroll
                for (int e = 0; e < 4; ++e) {
                    const int nbr = nn[e];
                    o[e] = (b + e < d)
                         ? (unsigned)((nbr >= node ? ORIG_OFF : 0) + nbr * FSB)
                         : (unsigned)DUMMY_ORIG;
                }
                const unsigned w0 = o[0] | (o[1] << 16);
                const unsigned w1 = o[2] | (o[3] << 16);
                opA[u] = make_uint2(w0, w1);
                opB[u] = make_uint2(w0 + 0x00040004u, w1 + 0x00040004u);
            }
        } else {
            ivwP[s] = make_float2(0.f, 1.f);
            selfP[s] = (unsigned short)(N_DRUG * FSB);
            #pragma unroll
            for (int u = 0; u < 8; ++u) {
                const unsigned wd = (unsigned)DUMMY_ORIG | ((unsigned)DUMMY_ORIG << 16);
                opA[u] = make_uint2(wd, wd);
                opB[u] = make_uint2(wd + 0x00040004u, wd + 0x00040004u);
            }
        }
    }

    // ---- stage orig; in-wave BN stats ----
    float sl = 0.f, ql = 0.f;
    for (int r = rg; r < N_DRUG; r += 32) {
        const float v = hout[(size_t)r * DIM + c0 + col];
        *(float*)(fsb + ORIG_OFF + r * FSB + cl4) = v;
        sl += v;
        ql = fmaf(v, v, ql);
    }
    if (lane < 3) {                                     // zero dummy rows
        *(float*)(fsb + N_DRUG * FSB + lane * 4) = 0.f;
        *(float*)(fsb + ORIG_OFF + N_DRUG * FSB + lane * 4) = 0.f;
    }
    #pragma unroll
    for (int off = 2; off <= 32; off <<= 1) {           // keep bit0 = col
        sl += __shfl_xor(sl, off, 64);
        ql += __shfl_xor(ql, off, 64);
    }
    const float mean = sl * (1.f / N_DRUG);
    const float var  = ql * (1.f / N_DRUG) - mean * mean;
    const float rstd = rsqrtf(var + 1e-5f);
    const float scl  = gamma[c0 + col] * rstd;
    const float shf  = beta[c0 + col] - mean * scl;

    for (int r = rg; r < N_DRUG; r += 32) {             // BN into orig[]
        float* p = (float*)(fsb + ORIG_OFF + r * FSB + cl4);
        *p = fmaf(*p, scl, shf);
    }

    // ---- rounds: single-wave, permuted schedule ----
    const bool smooth = (epoch[0] > 1);
    if (smooth) {
        const int j  = lane >> 2;          // slot within round 0..15
        const int hh = (lane >> 1) & 1;    // neighbor half
        const unsigned short* obase = col ? offsPB : offsPA;

        int base = 0;
        int cnt  = rcnt[0];
        int nct  = rcnt[1];
        int rp   = 2;
        uint4 ca, cb;
        {
            const uint4* p = (const uint4*)&obase[j * MAXDEG + hh * 16];
            ca = p[0]; cb = p[1];
        }
        unsigned scur = selfP[j];
        float  cur = *(const float*)(fsb + ORIG_OFF + scur + cl4);
        float2 iw  = ivwP[j];

        while (base < N_DRUG) {
            const bool pred = j < cnt;
            float s0 = 0.f, s1 = 0.f;
            if (pred) {
#define G2(W) { s0 += *(const float*)(fsb + (W & 0xffffu)); \
                s1 += *(const float*)(fsb + (W >> 16)); }
                G2(ca.x) G2(ca.y) G2(ca.z) G2(ca.w)
                G2(cb.x) G2(cb.y) G2(cb.z) G2(cb.w)
#undef G2
            }
            const int nbase = base + cnt;
            // prefetch next slot (orig/tables never written -> hazard-free)
            uint4 na, nb;
            {
                const uint4* p = (const uint4*)&obase[(nbase + j) * MAXDEG + hh * 16];
                na = p[0]; nb = p[1];
            }
            const unsigned nscur = selfP[nbase + j];
            const float  ncur = *(const float*)(fsb + ORIG_OFF + nscur + cl4);
            const float2 niw  = ivwP[nbase + j];
            const int    nnct = rcnt[rp];

            float nv = 0.f;
            if (pred) {
                float sh = s0 + s1;
                sh += __int_as_float(__builtin_amdgcn_mov_dpp(
                          __float_as_int(sh), 0x4E, 0xF, 0xF, false));  // lane^2
                nv = fmaf(sh, iw.x, cur * iw.y);
            }
            asm volatile("" ::: "memory");
            if (pred && hh == 0) *(float*)(fsb + scur + cl4) = nv;   // new[]
            asm volatile("" ::: "memory");
            base = nbase; cnt = nct; nct = nnct; ++rp;
            ca = na; cb = nb; scur = nscur; cur = ncur; iw = niw;
        }
    }

    // ---- write back ----
    const int rb = smooth ? 0 : ORIG_OFF;
    for (int r = rg; r < N_DRUG; r += 32)
        hout[(size_t)r * DIM + c0 + col] = *(const float*)(fsb + rb + r * FSB + cl4);
}

extern "C" void kernel_launch(void* const* d_in, const int* in_sizes, int n_in,
                              void* d_out, int out_size, void* d_ws, size_t ws_size,
                              hipStream_t stream)
{
    const float* drugW = (const float*)d_in[0];
    const float* relaW = (const float*)d_in[1];
    const float* entW  = (const float*)d_in[2];
    const float* Wa    = (const float*)d_in[3];
    const float* linW  = (const float*)d_in[4];
    const float* linb  = (const float*)d_in[5];
    const float* gamma = (const float*)d_in[6];
    const float* beta  = (const float*)d_in[7];
    const int* drug_name = (const int*)d_in[8];
    const int* adj_tail  = (const int*)d_in[9];
    const int* adj_rel   = (const int*)d_in[10];
    const int* nbr_idx   = (const int*)d_in[11];
    const int* nbr_deg   = (const int*)d_in[12];
    const int* epoch     = (const int*)d_in[13];

    float* out = (float*)d_out;    // h lives in d_out; scan updates in place

    // workspace layout (16B-aligned):
    //   linP  : 1024*512*4 = 2,097,152   @ 0
    //   relaP :  200*512*4 =   409,600   @ 2,097,152
    //   cat   : 572*1024*4 = 2,342,912   @ 2,506,752
    //   sched : 1152*4     =     4,608   @ 4,849,664   (total ~4.86 MB)
    float* linP   = (float*)d_ws;
    float* relaP  = (float*)((char*)d_ws + 2097152);
    float* cat    = (float*)((char*)d_ws + 2506752);
    int*   sched  = (int*)  ((char*)d_ws + 4849664);

    prep_kernel<<<929, 256, 0, stream>>>(Wa, relaW, linW, nbr_idx, nbr_deg,
                                         linP, relaP, sched);
    attn_kernel<<<N_DRUG, 256, 0, stream>>>(drugW, relaP, entW, drug_name,
                                            adj_tail, adj_rel, cat);
    gemm_h<<<dim3(72, 4), 512, 0, stream>>>(cat, linP, linb, out);
    scan_kernel<<<256, 64, 0, stream>>>(out, gamma, beta, nbr_idx, nbr_deg,
                                        epoch, sched);
}